// Round 13
// baseline (50.644 us; speedup 1.0000x reference)
//
#include <hip/hip_runtime.h>
#include <math.h>

#define EPSF 1e-5f
constexpr int NT  = 1024;
constexpr int ND  = 128;
constexpr int KIN = 19;
constexpr int H   = 256;
constexpr int L   = 128;

typedef __attribute__((ext_vector_type(8))) short short8;
typedef __attribute__((ext_vector_type(4))) float f32x4;

// packed fp32->bf16 (RNE), 2 elements per instruction
static __device__ inline unsigned cvt_pk_bf16(float lo, float hi) {
    unsigned r;
    asm("v_cvt_pk_bf16_f32 %0, %1, %2" : "=v"(r) : "v"(lo), "v"(hi));
    return r;
}

// ---------------------------------------------------------------------------
// Fused kernel A: persistent block over 4 g's (2 pairs), 1024 blocks.
// bfrag/basis built once per block; pair p+1's x/v loads issued before pair
// p's feature+MFMA phases (latency hidden); single-buffer LDS, 2 barriers/pair.
// ---------------------------------------------------------------------------
__global__ __launch_bounds__(256) void k_fused(
    const float* __restrict__ x0, const float* __restrict__ x,
    const int*   __restrict__ Nv, const float* __restrict__ basis,
    const float* __restrict__ v,  const float* __restrict__ W0,
    const float* __restrict__ b0, float* __restrict__ hm_out)
{
    const int tid  = threadIdx.x;
    const int lane = tid & 63;
    const int w    = tid >> 6;            // wave 0..3
    const int sub  = tid >> 7;            // which g of the current pair
    const int d    = tid & 127;
    const int gbase = blockIdx.x * 4;     // 4 g's per block
    const int bidx  = blockIdx.x >> 8;    // == g >> 10 for all 4 g's (no straddle)

    __shared__ __align__(16) ushort featb[2 * 512 * 8];   // 16 KB, single buffer
    __shared__ float psh[2][2][3];                        // per-g half-sums

    // ---- basis into registers once ----
    const float* bs = basis + bidx * 9;
    const float b0c = bs[0], b1c = bs[1], b2c = bs[2];
    const float b3c = bs[3], b4c = bs[4], b5c = bs[5];
    const float b6c = bs[6], b7c = bs[7], b8c = bs[8];

    // ---- B fragments once per wave (64-col group w) ----
    short8 bfrag[4];
    {
        const int col16 = lane & 15;
        const int kb    = lane >> 4;
        #pragma unroll
        for (int nt = 0; nt < 4; ++nt) {
            const int col = w * 64 + nt * 16 + col16;
            uint4 pk;
            #pragma unroll
            for (int jj = 0; jj < 4; ++jj) {
                const int k0 = kb * 8 + 2*jj;
                const int k1 = k0 + 1;
                const float a = (k0 < KIN) ? W0[k0 * H + col]
                               : ((k0 == KIN) ? b0[col] : 0.f);
                const float b = (k1 < KIN) ? W0[k1 * H + col]
                               : ((k1 == KIN) ? b0[col] : 0.f);
                (&pk.x)[jj] = cvt_pk_bf16(a, b);
            }
            bfrag[nt] = *reinterpret_cast<short8*>(&pk);
        }
    }

    // ---- preload pair 0's x/v for this thread ----
    float xx, xy, xz, vx, vy, vz;
    {
        const int g = gbase + sub;
        const float* xp = x + (size_t)g * (ND * 3) + d * 3;
        const float* vp = v + (size_t)g * (ND * 3) + d * 3;
        xx = xp[0]; xy = xp[1]; xz = xp[2];
        vx = vp[0]; vy = vp[1]; vz = vp[2];
    }

    const f32x4 zc = {0.f, 0.f, 0.f, 0.f};
    const float invd = 1.0f / (float)ND;

    #pragma unroll
    for (int p = 0; p < 2; ++p) {
        const int gp2 = gbase + p * 2;
        const int g   = gp2 + sub;

        // ---- issue NEXT pair's loads early (latency hides under this pair) ----
        float nxx = 0.f, nxy = 0.f, nxz = 0.f, nvx = 0.f, nvy = 0.f, nvz = 0.f;
        if (p == 0) {
            const int gn = gbase + 2 + sub;
            const float* xp = x + (size_t)gn * (ND * 3) + d * 3;
            const float* vp = v + (size_t)gn * (ND * 3) + d * 3;
            nxx = xp[0]; nxy = xp[1]; nxz = xp[2];
            nvx = vp[0]; nvy = vp[1]; nvz = vp[2];
        }

        // ---- v0 reduce (wave shfl + LDS half-combine) ----
        float sx = vx, sy = vy, sz = vz;
        #pragma unroll
        for (int m = 1; m < 64; m <<= 1) {
            sx += __shfl_xor(sx, m, 64);
            sy += __shfl_xor(sy, m, 64);
            sz += __shfl_xor(sz, m, 64);
        }
        if (lane == 0) {
            psh[sub][w & 1][0] = sx;
            psh[sub][w & 1][1] = sy;
            psh[sub][w & 1][2] = sz;
        }
        __syncthreads();                       // barrier 1
        const float v0x = (psh[sub][0][0] + psh[sub][1][0]) * invd;
        const float v0y = (psh[sub][0][1] + psh[sub][1][1]) * invd;
        const float v0z = (psh[sub][0][2] + psh[sub][1][2]) * invd;

        // ---- block-uniform scalars ----
        unsigned u0, u1, u2, u3, u4;
        {
            const float ax = x0[g*3+0], ay = x0[g*3+1], az = x0[g*3+2];
            const float x0n = sqrtf(ax*ax + ay*ay + az*az) + EPSF;
            const float v0n = sqrtf(v0x*v0x + v0y*v0y + v0z*v0z) + EPSF;
            const float ix  = 1.f / x0n, iv0 = 1.f / v0n;
            u0 = cvt_pk_bf16(log1pf((float)Nv[g]), x0n);
            u1 = cvt_pk_bf16((ax*b0c + ay*b1c + az*b2c) * ix,
                             (ax*b3c + ay*b4c + az*b5c) * ix);
            u2 = cvt_pk_bf16((ax*b6c + ay*b7c + az*b8c) * ix, v0n);
            u3 = cvt_pk_bf16((v0x*b0c + v0y*b1c + v0z*b2c) * iv0,
                             (v0x*b3c + v0y*b4c + v0z*b5c) * iv0);
            u4 = cvt_pk_bf16((v0x*b6c + v0y*b7c + v0z*b8c) * iv0,
                             (ax*v0x + ay*v0y + az*v0z) * ix * iv0);
        }
        // ---- per-d feats ----
        unsigned u5, u6, u7, u8, u9;
        {
            const float cx = vx - v0x, cy = vy - v0y, cz = vz - v0z;
            const float xn = sqrtf(xx*xx + xy*xy + xz*xz) + EPSF;
            const float vn = sqrtf(cx*cx + cy*cy + cz*cz) + EPSF;
            const float ixn = 1.f/xn, ivn = 1.f/vn;
            u5 = cvt_pk_bf16(xn, (xx*b0c + xy*b1c + xz*b2c) * ixn);
            u6 = cvt_pk_bf16((xx*b3c + xy*b4c + xz*b5c) * ixn,
                             (xx*b6c + xy*b7c + xz*b8c) * ixn);
            u7 = cvt_pk_bf16(vn, (cx*b0c + cy*b1c + cz*b2c) * ivn);
            u8 = cvt_pk_bf16((cx*b3c + cy*b4c + cz*b5c) * ivn,
                             (cx*b6c + cy*b7c + cz*b8c) * ivn);
            u9 = cvt_pk_bf16((xx*cx + xy*cy + xz*cz) * ixn * ivn, 1.0f);
        }

        const int mt  = d >> 4;
        const int r16 = d & 15;
        uint4* base = reinterpret_cast<uint4*>(
            &featb[((sub << 9) + (mt << 6) + r16) * 8]);
        base[0]  = uint4{u0, u1, u2, u3};          // kb=0 (k0..7)
        base[16] = uint4{u4, u5, u6, u7};          // kb=1 (k8..15)
        base[32] = uint4{u8, u9, 0u, 0u};          // kb=2 (k16..19,0,0)
        if (p == 0) base[48] = uint4{0u, 0u, 0u, 0u};  // kb=3 zero, once
        __syncthreads();                       // barrier 2

        // ---- MFMA over both g's of the pair, interleaved ----
        float a00 = 0.f, a01 = 0.f, a02 = 0.f, a03 = 0.f;
        float a10 = 0.f, a11 = 0.f, a12 = 0.f, a13 = 0.f;

        #pragma unroll 2
        for (int m2 = 0; m2 < 8; ++m2) {
            const short8 af0 = *reinterpret_cast<const short8*>(
                &featb[((m2 << 6) + lane) * 8]);
            const short8 af1 = *reinterpret_cast<const short8*>(
                &featb[(512 + (m2 << 6) + lane) * 8]);
            {
                f32x4 d0 = __builtin_amdgcn_mfma_f32_16x16x32_bf16(af0, bfrag[0], zc, 0, 0, 0);
                f32x4 d1 = __builtin_amdgcn_mfma_f32_16x16x32_bf16(af1, bfrag[0], zc, 0, 0, 0);
                #pragma unroll
                for (int r = 0; r < 4; ++r) {
                    a00 = fmaf(0.505f, d0[r], fmaf(0.495f, fabsf(d0[r]), a00));
                    a10 = fmaf(0.505f, d1[r], fmaf(0.495f, fabsf(d1[r]), a10));
                }
            }
            {
                f32x4 d0 = __builtin_amdgcn_mfma_f32_16x16x32_bf16(af0, bfrag[1], zc, 0, 0, 0);
                f32x4 d1 = __builtin_amdgcn_mfma_f32_16x16x32_bf16(af1, bfrag[1], zc, 0, 0, 0);
                #pragma unroll
                for (int r = 0; r < 4; ++r) {
                    a01 = fmaf(0.505f, d0[r], fmaf(0.495f, fabsf(d0[r]), a01));
                    a11 = fmaf(0.505f, d1[r], fmaf(0.495f, fabsf(d1[r]), a11));
                }
            }
            {
                f32x4 d0 = __builtin_amdgcn_mfma_f32_16x16x32_bf16(af0, bfrag[2], zc, 0, 0, 0);
                f32x4 d1 = __builtin_amdgcn_mfma_f32_16x16x32_bf16(af1, bfrag[2], zc, 0, 0, 0);
                #pragma unroll
                for (int r = 0; r < 4; ++r) {
                    a02 = fmaf(0.505f, d0[r], fmaf(0.495f, fabsf(d0[r]), a02));
                    a12 = fmaf(0.505f, d1[r], fmaf(0.495f, fabsf(d1[r]), a12));
                }
            }
            {
                f32x4 d0 = __builtin_amdgcn_mfma_f32_16x16x32_bf16(af0, bfrag[3], zc, 0, 0, 0);
                f32x4 d1 = __builtin_amdgcn_mfma_f32_16x16x32_bf16(af1, bfrag[3], zc, 0, 0, 0);
                #pragma unroll
                for (int r = 0; r < 4; ++r) {
                    a03 = fmaf(0.505f, d0[r], fmaf(0.495f, fabsf(d0[r]), a03));
                    a13 = fmaf(0.505f, d1[r], fmaf(0.495f, fabsf(d1[r]), a13));
                }
            }
        }

        // ---- epilogue: column pool, write hm for both g's of the pair ----
        {
            float sv0[4] = {a00, a01, a02, a03};
            float sv1[4] = {a10, a11, a12, a13};
            #pragma unroll
            for (int nt = 0; nt < 4; ++nt) {
                float s4 = sv0[nt];
                s4 += __shfl_xor(s4, 16, 64);
                s4 += __shfl_xor(s4, 32, 64);
                float s5 = sv1[nt];
                s5 += __shfl_xor(s5, 16, 64);
                s5 += __shfl_xor(s5, 32, 64);
                if (lane < 16) {
                    hm_out[(size_t)(gp2 + 0) * H + w * 64 + nt * 16 + lane] = s4 * invd;
                    hm_out[(size_t)(gp2 + 1) * H + w * 64 + nt * 16 + lane] = s5 * invd;
                }
            }
        }

        // ---- rotate preloaded regs for next pair ----
        xx = nxx; xy = nxy; xz = nxz;
        vx = nvx; vy = nvy; vz = nvz;
    }
}

// ---------------------------------------------------------------------------
// Kernel B: layers 1-2, 8 t per block (unchanged, near L2-BW roofline)
// ---------------------------------------------------------------------------
__global__ __launch_bounds__(256) void k_l12(
    const float* __restrict__ hm, const float* __restrict__ W1,
    const float* __restrict__ b1, const float* __restrict__ W2,
    const float* __restrict__ b2, float* __restrict__ out)
{
    const int tb  = blockIdx.x * 8;
    const int tid = threadIdx.x;
    __shared__ float hs[8][H];
    __shared__ float h1[8][H];

    {
        const float4* src = reinterpret_cast<const float4*>(hm + (size_t)tb * H);
        float4* dst = reinterpret_cast<float4*>(&hs[0][0]);
        #pragma unroll
        for (int i = 0; i < 2; ++i) dst[tid + i*256] = src[tid + i*256];
    }
    __syncthreads();

    {
        float acc[8];
        const float bb = b1[tid];
        #pragma unroll
        for (int t = 0; t < 8; ++t) acc[t] = bb;
        for (int k = 0; k < H; ++k) {
            const float w = W1[(size_t)k * H + tid];
            #pragma unroll
            for (int t = 0; t < 8; ++t) acc[t] = fmaf(hs[t][k], w, acc[t]);
        }
        #pragma unroll
        for (int t = 0; t < 8; ++t) {
            float a = acc[t];
            h1[t][tid] = (a > 0.f) ? a : 0.01f * a;
        }
    }
    __syncthreads();

    {
        const int n  = tid & 127;
        const int t0 = (tid >> 7) * 4;
        float acc[4];
        const float bb = b2[n];
        #pragma unroll
        for (int t = 0; t < 4; ++t) acc[t] = bb;
        for (int k = 0; k < H; ++k) {
            const float w = W2[(size_t)k * L + n];
            #pragma unroll
            for (int t = 0; t < 4; ++t) acc[t] = fmaf(h1[t0 + t][k], w, acc[t]);
        }
        #pragma unroll
        for (int t = 0; t < 4; ++t)
            out[(size_t)(tb + t0 + t) * L + n] = acc[t];
    }
}

extern "C" void kernel_launch(void* const* d_in, const int* in_sizes, int n_in,
                              void* d_out, int out_size, void* d_ws, size_t ws_size,
                              hipStream_t stream) {
    const float* x0    = (const float*)d_in[0];
    const float* x     = (const float*)d_in[1];
    const int*   Nv    = (const int*)  d_in[2];
    const float* basis = (const float*)d_in[3];
    const float* v     = (const float*)d_in[4];
    const float* W0    = (const float*)d_in[5];
    const float* b0    = (const float*)d_in[6];
    const float* W1    = (const float*)d_in[7];
    const float* b1    = (const float*)d_in[8];
    const float* W2    = (const float*)d_in[9];
    const float* b2    = (const float*)d_in[10];
    float* out = (float*)d_out;
    float* hm  = (float*)d_ws;          // 4096*256*4 = 4 MB

    hipLaunchKernelGGL(k_fused, dim3(4 * NT / 4), dim3(256), 0, stream,
                       x0, x, Nv, basis, v, W0, b0, hm);
    hipLaunchKernelGGL(k_l12, dim3(4 * NT / 8), dim3(256), 0, stream,
                       hm, W1, b1, W2, b2, out);
}